// Round 1
// baseline (495.521 us; speedup 1.0000x reference)
//
#include <hip/hip_runtime.h>
#include <math.h>

// Problem constants (B=2, C=64, CI=32, T=16, H=W=14)
#define S3   3136      // T*H*W = 16*196
#define PB   100352    // per-batch proj elements = CI*T*H*W = 16*6272
#define XB   200704    // per-batch x elements = C*T*H*W
#define NN   6272      // CI*H*W (spatial attention sequence length)

// ---------------------------------------------------------------------------
// Kernel 1: all 6 QKV projections.  out[b,o,s] = sum_c x[b,c,s]*W[o,c] + bias[o]
// Spatial projections (p=0,1,2) stored TRANSPOSED as P[n*16+t] where
// j = o*3136+s, t = j/6272 = o>>1, n = j%6272 = (o&1)*3136+s.
// Temporal projections (p=3,4,5) stored in natural j layout.
// Weights read directly from global with uniform indices -> s_load + K$.
// ---------------------------------------------------------------------------
__global__ __launch_bounds__(256) void proj_kernel(
    const float* __restrict__ x,
    const float* __restrict__ W0, const float* __restrict__ b0,
    const float* __restrict__ W1, const float* __restrict__ b1,
    const float* __restrict__ W2, const float* __restrict__ b2,
    const float* __restrict__ W3, const float* __restrict__ b3,
    const float* __restrict__ W4, const float* __restrict__ b4,
    const float* __restrict__ W5, const float* __restrict__ b5,
    float* __restrict__ Qst, float* __restrict__ Kst, float* __restrict__ Vst,
    float* __restrict__ Qt,  float* __restrict__ Kt,  float* __restrict__ Vt)
{
    const float* Wp; const float* bp; float* op; int tr;
    switch (blockIdx.y) {
        case 0:  Wp = W0; bp = b0; op = Qst; tr = 1; break;
        case 1:  Wp = W1; bp = b1; op = Kst; tr = 1; break;
        case 2:  Wp = W2; bp = b2; op = Vst; tr = 1; break;
        case 3:  Wp = W3; bp = b3; op = Qt;  tr = 0; break;
        case 4:  Wp = W4; bp = b4; op = Kt;  tr = 0; break;
        default: Wp = W5; bp = b5; op = Vt;  tr = 0; break;
    }

    int gid = blockIdx.x * 256 + threadIdx.x;
    if (gid >= 2 * S3) return;
    int b = (gid >= S3) ? 1 : 0;
    int s = gid - b * S3;

    // load this spatial column of x into registers (coalesced across lanes)
    float xr[64];
    #pragma unroll
    for (int c = 0; c < 64; ++c) xr[c] = x[(size_t)b * XB + (size_t)c * S3 + s];

    float a[32];
    #pragma unroll
    for (int o = 0; o < 32; ++o) {
        float acc = bp[o];
        #pragma unroll
        for (int c = 0; c < 64; ++c) acc = fmaf(Wp[o * 64 + c], xr[c], acc);
        a[o] = acc;
    }

    if (tr) {
        // transposed store: for h in {0,1}: n = h*3136+s, value at t comes from o=2t+h
        float* obase = op + (size_t)b * PB;
        #pragma unroll
        for (int h = 0; h < 2; ++h) {
            int n = h * S3 + s;
            float4* o4 = (float4*)(obase + (size_t)n * 16);
            o4[0] = make_float4(a[0 + h],  a[2 + h],  a[4 + h],  a[6 + h]);
            o4[1] = make_float4(a[8 + h],  a[10 + h], a[12 + h], a[14 + h]);
            o4[2] = make_float4(a[16 + h], a[18 + h], a[20 + h], a[22 + h]);
            o4[3] = make_float4(a[24 + h], a[26 + h], a[28 + h], a[30 + h]);
        }
    } else {
        float* obase = op + (size_t)b * PB;
        #pragma unroll
        for (int o = 0; o < 32; ++o) obase[(size_t)o * S3 + s] = a[o];
    }
}

// ---------------------------------------------------------------------------
// Kernel 2: spatial attention, flash-style without max (logits are O(1)):
//   per row n:  l = sum_m exp(0.25*q.k_m),  acc[t] = sum_m exp(...)*v_m[t]
//   Y[t*6272+n] = acc[t]/l
// 512 threads = 8 waves; wave g handles m in [g*784,(g+1)*784); lane = row.
// k/v columns are 16 contiguous floats at wave-uniform addresses -> scalar loads.
// ---------------------------------------------------------------------------
__global__ __launch_bounds__(512) void spatial_attn(
    const float* __restrict__ Qst, const float* __restrict__ Kst,
    const float* __restrict__ Vst, float* __restrict__ YS)
{
    __shared__ float sh[17 * 512];

    int b = blockIdx.y;
    int r = threadIdx.x & 63;
    int g = __builtin_amdgcn_readfirstlane((int)(threadIdx.x >> 6));  // wave-uniform
    int n = blockIdx.x * 64 + r;

    // load q row (16 contiguous floats, coalesced across lanes)
    float q[16];
    {
        const float4* qp = (const float4*)(Qst + (size_t)b * PB + (size_t)n * 16);
        float4 q0 = qp[0], q1 = qp[1], q2 = qp[2], q3 = qp[3];
        q[0] = q0.x; q[1] = q0.y; q[2]  = q0.z; q[3]  = q0.w;
        q[4] = q1.x; q[5] = q1.y; q[6]  = q1.z; q[7]  = q1.w;
        q[8] = q2.x; q[9] = q2.y; q[10] = q2.z; q[11] = q2.w;
        q[12] = q3.x; q[13] = q3.y; q[14] = q3.z; q[15] = q3.w;
    }

    float acc[16];
    #pragma unroll
    for (int t = 0; t < 16; ++t) acc[t] = 0.0f;
    float l = 0.0f;

    const float* Kbase = Kst + (size_t)b * PB;
    const float* Vbase = Vst + (size_t)b * PB;

    int m0 = g * 784;
    int m1 = m0 + 784;
    #pragma unroll 2
    for (int m = m0; m < m1; ++m) {
        const float4* kp = (const float4*)(Kbase + (size_t)m * 16);
        float4 ka = kp[0], kb = kp[1], kc = kp[2], kd = kp[3];
        const float4* vp = (const float4*)(Vbase + (size_t)m * 16);
        float4 va = vp[0], vb = vp[1], vc = vp[2], vd = vp[3];

        float s0 = fmaf(q[3],  ka.w, fmaf(q[2],  ka.z, fmaf(q[1],  ka.y, q[0]  * ka.x)));
        float s1 = fmaf(q[7],  kb.w, fmaf(q[6],  kb.z, fmaf(q[5],  kb.y, q[4]  * kb.x)));
        float s2 = fmaf(q[11], kc.w, fmaf(q[10], kc.z, fmaf(q[9],  kc.y, q[8]  * kc.x)));
        float s3 = fmaf(q[15], kd.w, fmaf(q[14], kd.z, fmaf(q[13], kd.y, q[12] * kd.x)));
        float sdot = (s0 + s1) + (s2 + s3);

        float p = __expf(0.25f * sdot);
        l += p;

        acc[0]  = fmaf(p, va.x, acc[0]);  acc[1]  = fmaf(p, va.y, acc[1]);
        acc[2]  = fmaf(p, va.z, acc[2]);  acc[3]  = fmaf(p, va.w, acc[3]);
        acc[4]  = fmaf(p, vb.x, acc[4]);  acc[5]  = fmaf(p, vb.y, acc[5]);
        acc[6]  = fmaf(p, vb.z, acc[6]);  acc[7]  = fmaf(p, vb.w, acc[7]);
        acc[8]  = fmaf(p, vc.x, acc[8]);  acc[9]  = fmaf(p, vc.y, acc[9]);
        acc[10] = fmaf(p, vc.z, acc[10]); acc[11] = fmaf(p, vc.w, acc[11]);
        acc[12] = fmaf(p, vd.x, acc[12]); acc[13] = fmaf(p, vd.y, acc[13]);
        acc[14] = fmaf(p, vd.z, acc[14]); acc[15] = fmaf(p, vd.w, acc[15]);
    }

    // merge 8 wave-partials per row (plain sums — no max bookkeeping needed)
    #pragma unroll
    for (int t = 0; t < 16; ++t) sh[t * 512 + threadIdx.x] = acc[t];
    sh[16 * 512 + threadIdx.x] = l;
    __syncthreads();

    if (threadIdx.x < 64) {
        float lt = 0.0f;
        #pragma unroll
        for (int w = 0; w < 8; ++w) lt += sh[16 * 512 + w * 64 + threadIdx.x];
        float inv = 1.0f / lt;
        float* yp = YS + (size_t)b * PB;
        int nn = blockIdx.x * 64 + threadIdx.x;
        #pragma unroll
        for (int t = 0; t < 16; ++t) {
            float a = 0.0f;
            #pragma unroll
            for (int w = 0; w < 8; ++w) a += sh[t * 512 + w * 64 + threadIdx.x];
            yp[(size_t)t * NN + nn] = a * inv;   // natural (CI,T,H,W) flat layout
        }
    }
}

// ---------------------------------------------------------------------------
// Kernel 3: temporal Gram partials  G[t][s] = sum_n Qt[n*16+t]*Kt[n*16+s]
// grid (32 n-chunks, 2 batches); thread = (t,s) pair; chunk = 196 n's.
// ---------------------------------------------------------------------------
__global__ __launch_bounds__(256) void temporal_g(
    const float* __restrict__ Qt, const float* __restrict__ Kt,
    float* __restrict__ Gpart)
{
    int b = blockIdx.y, c = blockIdx.x;
    int t = threadIdx.x >> 4, s = threadIdx.x & 15;
    const float* qb = Qt + (size_t)b * PB;
    const float* kb = Kt + (size_t)b * PB;
    float acc = 0.0f;
    int n0 = c * 196;
    #pragma unroll 4
    for (int i = 0; i < 196; ++i) {
        int n = n0 + i;
        acc = fmaf(qb[n * 16 + t], kb[n * 16 + s], acc);
    }
    Gpart[(size_t)(b * 32 + c) * 256 + threadIdx.x] = acc;
}

// ---------------------------------------------------------------------------
// Kernel 4: reduce partials + row softmax (WITH max: these logits have std~20)
// ---------------------------------------------------------------------------
__global__ __launch_bounds__(256) void temporal_soft(
    const float* __restrict__ Gpart, float* __restrict__ At)
{
    int b = blockIdx.x;
    __shared__ float L[256];
    float acc = 0.0f;
    #pragma unroll
    for (int c = 0; c < 32; ++c) acc += Gpart[(size_t)(b * 32 + c) * 256 + threadIdx.x];
    L[threadIdx.x] = acc * 0.25f;
    __syncthreads();
    if (threadIdx.x < 16) {
        int t = threadIdx.x;
        float mx = -1e30f;
        #pragma unroll
        for (int s = 0; s < 16; ++s) mx = fmaxf(mx, L[t * 16 + s]);
        float e[16]; float sm = 0.0f;
        #pragma unroll
        for (int s = 0; s < 16; ++s) { e[s] = __expf(L[t * 16 + s] - mx); sm += e[s]; }
        float inv = 1.0f / sm;
        #pragma unroll
        for (int s = 0; s < 16; ++s) At[b * 256 + t * 16 + s] = e[s] * inv;
    }
}

// ---------------------------------------------------------------------------
// Kernel 5: y = ys + yt (yt computed on the fly from At,Vt), then
// out = x + bw + Ww . y     (final 1x1x1 conv + residual)
// ---------------------------------------------------------------------------
__global__ __launch_bounds__(256) void final_kernel(
    const float* __restrict__ x, const float* __restrict__ Ww,
    const float* __restrict__ bw, const float* __restrict__ YS,
    const float* __restrict__ Vt, const float* __restrict__ At,
    float* __restrict__ out)
{
    // At staged transposed: Alt[b][s2][t] so lane-varying t hits consecutive banks
    __shared__ float Alt[2][16][16];
    for (int i = threadIdx.x; i < 512; i += 256) {
        int bb = i >> 8, t = (i >> 4) & 15, s2 = i & 15;
        Alt[bb][s2][t] = At[i];
    }
    __syncthreads();

    int gid = blockIdx.x * 256 + threadIdx.x;
    if (gid >= 2 * S3) return;
    int b = (gid >= S3) ? 1 : 0;
    int s = gid - b * S3;

    float y[32];
    #pragma unroll
    for (int ci = 0; ci < 32; ++ci) {
        int j = ci * S3 + s;
        int t = j & 15;
        float yv = YS[(size_t)b * PB + j];
        const float* vp = Vt + (size_t)b * PB + (j & ~15);
        #pragma unroll
        for (int s2 = 0; s2 < 16; ++s2) yv = fmaf(Alt[b][s2][t], vp[s2], yv);
        y[ci] = yv;
    }

    #pragma unroll
    for (int c = 0; c < 64; ++c) {
        float acc = bw[c];
        #pragma unroll
        for (int ci = 0; ci < 32; ++ci) acc = fmaf(Ww[c * 32 + ci], y[ci], acc);
        out[(size_t)b * XB + (size_t)c * S3 + s] = x[(size_t)b * XB + (size_t)c * S3 + s] + acc;
    }
}

// ---------------------------------------------------------------------------
extern "C" void kernel_launch(void* const* d_in, const int* in_sizes, int n_in,
                              void* d_out, int out_size, void* d_ws, size_t ws_size,
                              hipStream_t stream)
{
    const float* x   = (const float*)d_in[0];
    const float* Wqs = (const float*)d_in[1];  const float* bqs = (const float*)d_in[2];
    const float* Wks = (const float*)d_in[3];  const float* bks = (const float*)d_in[4];
    const float* Wvs = (const float*)d_in[5];  const float* bvs = (const float*)d_in[6];
    const float* Wqt = (const float*)d_in[7];  const float* bqt = (const float*)d_in[8];
    const float* Wkt = (const float*)d_in[9];  const float* bkt = (const float*)d_in[10];
    const float* Wvt = (const float*)d_in[11]; const float* bvt = (const float*)d_in[12];
    const float* Ww  = (const float*)d_in[13]; const float* bw  = (const float*)d_in[14];

    // workspace layout (floats); total 1,421,824 floats = 5.69 MB
    float* ws  = (float*)d_ws;
    float* Qst = ws;             // 200704 (transposed spatial Q)
    float* Kst = ws + 200704;    // 200704
    float* Vst = ws + 401408;    // 200704
    float* Qt  = ws + 602112;    // 200704 (natural layout)
    float* Kt  = ws + 802816;    // 200704
    float* Vt  = ws + 1003520;   // 200704
    float* YS  = ws + 1204224;   // 200704 (spatial attn output, natural layout)
    float* Gp  = ws + 1404928;   // 16384  (temporal Gram partials)
    float* At  = ws + 1421312;   // 512    (temporal attention matrix)

    proj_kernel<<<dim3(25, 6), 256, 0, stream>>>(
        x, Wqs, bqs, Wks, bks, Wvs, bvs, Wqt, bqt, Wkt, bkt, Wvt, bvt,
        Qst, Kst, Vst, Qt, Kt, Vt);

    spatial_attn<<<dim3(98, 2), 512, 0, stream>>>(Qst, Kst, Vst, YS);

    temporal_g<<<dim3(32, 2), 256, 0, stream>>>(Qt, Kt, Gp);
    temporal_soft<<<2, 256, 0, stream>>>(Gp, At);

    final_kernel<<<dim3(25, 1), 256, 0, stream>>>(x, Ww, bw, YS, Vt, At, (float*)d_out);
}

// Round 2
// 255.798 us; speedup vs baseline: 1.9372x; 1.9372x over previous
//
#include <hip/hip_runtime.h>
#include <math.h>

// Problem constants (B=2, C=64, CI=32, T=16, H=W=14)
#define S3   3136      // H*W*T-group = 16*196 (per-channel spatial size)
#define PB   100352    // per-batch proj elements = 32*3136
#define XB   200704    // per-batch x elements = 64*3136
#define NN   6272      // CI*H*W = spatial attention sequence length

// ---------------------------------------------------------------------------
// Kernel 1: all 6 QKV projections, split 2x over output channels.
// out[b,o,s] = sum_c x[b,c,s]*W[o,c] + bias[o]
// Spatial projections (y=0,1,2) stored TRANSPOSED as P[n*16+t] (t=o>>1,
// n=(o&1)*3136+s); temporal (y=3,4,5) in natural flat layout.
// ---------------------------------------------------------------------------
__global__ __launch_bounds__(256) void proj_kernel(
    const float* __restrict__ x,
    const float* __restrict__ W0, const float* __restrict__ b0,
    const float* __restrict__ W1, const float* __restrict__ b1,
    const float* __restrict__ W2, const float* __restrict__ b2,
    const float* __restrict__ W3, const float* __restrict__ b3,
    const float* __restrict__ W4, const float* __restrict__ b4,
    const float* __restrict__ W5, const float* __restrict__ b5,
    float* __restrict__ Qst, float* __restrict__ Kst, float* __restrict__ Vst,
    float* __restrict__ Qt,  float* __restrict__ Kt,  float* __restrict__ Vt)
{
    const float* Wp; const float* bp; float* op; int tr;
    switch (blockIdx.y) {
        case 0:  Wp = W0; bp = b0; op = Qst; tr = 1; break;
        case 1:  Wp = W1; bp = b1; op = Kst; tr = 1; break;
        case 2:  Wp = W2; bp = b2; op = Vst; tr = 1; break;
        case 3:  Wp = W3; bp = b3; op = Qt;  tr = 0; break;
        case 4:  Wp = W4; bp = b4; op = Kt;  tr = 0; break;
        default: Wp = W5; bp = b5; op = Vt;  tr = 0; break;
    }
    int z = blockIdx.z;               // o-half: o in [z*16, z*16+16)

    int gid = blockIdx.x * 256 + threadIdx.x;
    if (gid >= 2 * S3) return;
    int b = (gid >= S3) ? 1 : 0;
    int s = gid - b * S3;

    float xr[64];
    #pragma unroll
    for (int c = 0; c < 64; ++c) xr[c] = x[(size_t)b * XB + (size_t)c * S3 + s];

    float a[16];
    #pragma unroll
    for (int oo = 0; oo < 16; ++oo) {
        int o = z * 16 + oo;
        float acc = bp[o];
        #pragma unroll
        for (int c = 0; c < 64; ++c) acc = fmaf(Wp[o * 64 + c], xr[c], acc);
        a[oo] = acc;
    }

    float* obase = op + (size_t)b * PB;
    if (tr) {
        // o = z*16 + 2k + h  ->  t = z*8+k ; local a index = 2k+h
        #pragma unroll
        for (int h = 0; h < 2; ++h) {
            int n = h * S3 + s;
            float4* o4 = (float4*)(obase + (size_t)n * 16);
            o4[z * 2 + 0] = make_float4(a[0 + h], a[2 + h],  a[4 + h],  a[6 + h]);
            o4[z * 2 + 1] = make_float4(a[8 + h], a[10 + h], a[12 + h], a[14 + h]);
        }
    } else {
        #pragma unroll
        for (int oo = 0; oo < 16; ++oo) obase[(size_t)(z * 16 + oo) * S3 + s] = a[oo];
    }
}

// ---------------------------------------------------------------------------
// Kernel 2: spatial attention partials. Grid (98, W/4, 2), block 256 (4 waves).
// Wave handles 64 rows (lane=row) x one m-chunk of 6272/W columns.
// k/v columns are 16 contiguous floats at wave-uniform addresses (L1 bcast).
// No max-subtraction: logits are O(1) (verified: absmax passed without it).
// ---------------------------------------------------------------------------
__global__ __launch_bounds__(256) void spatial_attn(
    const float* __restrict__ Qst, const float* __restrict__ Kst,
    const float* __restrict__ Vst, float* __restrict__ Pacc,
    float* __restrict__ Pl, int W, int mPerWave)
{
    int b = blockIdx.z;
    int r = threadIdx.x & 63;
    int wv = __builtin_amdgcn_readfirstlane(
        blockIdx.y * 4 + (int)(threadIdx.x >> 6));   // m-chunk id, wave-uniform
    int n = blockIdx.x * 64 + r;

    float q[16];
    {
        const float4* qp = (const float4*)(Qst + (size_t)b * PB + (size_t)n * 16);
        float4 q0 = qp[0], q1 = qp[1], q2 = qp[2], q3 = qp[3];
        q[0]  = q0.x; q[1]  = q0.y; q[2]  = q0.z; q[3]  = q0.w;
        q[4]  = q1.x; q[5]  = q1.y; q[6]  = q1.z; q[7]  = q1.w;
        q[8]  = q2.x; q[9]  = q2.y; q[10] = q2.z; q[11] = q2.w;
        q[12] = q3.x; q[13] = q3.y; q[14] = q3.z; q[15] = q3.w;
    }
    #pragma unroll
    for (int t = 0; t < 16; ++t) q[t] *= 0.25f;    // fold softmax scale into q

    float acc[16];
    #pragma unroll
    for (int t = 0; t < 16; ++t) acc[t] = 0.0f;
    float l = 0.0f;

    const float* Kbase = Kst + (size_t)b * PB;
    const float* Vbase = Vst + (size_t)b * PB;

    int m0 = wv * mPerWave;
    int m1 = m0 + mPerWave;
    #pragma unroll 4
    for (int m = m0; m < m1; ++m) {
        const float4* kp = (const float4*)(Kbase + (size_t)m * 16);
        float4 ka = kp[0], kb = kp[1], kc = kp[2], kd = kp[3];
        const float4* vp = (const float4*)(Vbase + (size_t)m * 16);
        float4 va = vp[0], vb = vp[1], vc = vp[2], vd = vp[3];

        float s0 = fmaf(q[3],  ka.w, fmaf(q[2],  ka.z, fmaf(q[1],  ka.y, q[0]  * ka.x)));
        float s1 = fmaf(q[7],  kb.w, fmaf(q[6],  kb.z, fmaf(q[5],  kb.y, q[4]  * kb.x)));
        float s2 = fmaf(q[11], kc.w, fmaf(q[10], kc.z, fmaf(q[9],  kc.y, q[8]  * kc.x)));
        float s3 = fmaf(q[15], kd.w, fmaf(q[14], kd.z, fmaf(q[13], kd.y, q[12] * kd.x)));
        float p = __expf((s0 + s1) + (s2 + s3));
        l += p;

        acc[0]  = fmaf(p, va.x, acc[0]);  acc[1]  = fmaf(p, va.y, acc[1]);
        acc[2]  = fmaf(p, va.z, acc[2]);  acc[3]  = fmaf(p, va.w, acc[3]);
        acc[4]  = fmaf(p, vb.x, acc[4]);  acc[5]  = fmaf(p, vb.y, acc[5]);
        acc[6]  = fmaf(p, vb.z, acc[6]);  acc[7]  = fmaf(p, vb.w, acc[7]);
        acc[8]  = fmaf(p, vc.x, acc[8]);  acc[9]  = fmaf(p, vc.y, acc[9]);
        acc[10] = fmaf(p, vc.z, acc[10]); acc[11] = fmaf(p, vc.w, acc[11]);
        acc[12] = fmaf(p, vd.x, acc[12]); acc[13] = fmaf(p, vd.y, acc[13]);
        acc[14] = fmaf(p, vd.z, acc[14]); acc[15] = fmaf(p, vd.w, acc[15]);
    }

    // partials: Pacc[((b*16+t)*W + wv)*6272 + n], Pl[(b*W+wv)*6272 + n]
    #pragma unroll
    for (int t = 0; t < 16; ++t)
        Pacc[((size_t)(b * 16 + t) * W + wv) * NN + n] = acc[t];
    Pl[((size_t)b * W + wv) * NN + n] = l;
}

// ---------------------------------------------------------------------------
// Kernel 3: merge spatial partials, divide by l, fuse temporal-branch yt add.
// thread per output element idx in [0, 2*PB): Y[idx] = ys + yt.
// ---------------------------------------------------------------------------
__global__ __launch_bounds__(256) void spatial_merge(
    const float* __restrict__ Pacc, const float* __restrict__ Pl,
    const float* __restrict__ Vt, const float* __restrict__ At,
    float* __restrict__ Y, int W)
{
    __shared__ float Ash[2][16][16];   // [b][s][t2] (transposed for bank-free read)
    for (int i = threadIdx.x; i < 512; i += 256) {
        int bb = i >> 8, ss = (i >> 4) & 15, t2 = i & 15;
        Ash[bb][ss][t2] = At[bb * 256 + t2 * 16 + ss];
    }
    __syncthreads();

    int idx = blockIdx.x * 256 + threadIdx.x;     // < 200704
    int b = (idx >= PB) ? 1 : 0;
    int j = idx - b * PB;
    int t = j / NN;
    int nn = j - t * NN;

    float a = 0.0f, l = 0.0f;
    for (int w = 0; w < W; ++w) {
        a += Pacc[((size_t)(b * 16 + t) * W + w) * NN + nn];
        l += Pl[((size_t)b * W + w) * NN + nn];
    }
    float ys = a / l;

    int t2 = nn & 15;
    const float* vp = Vt + (size_t)b * PB + (size_t)t * NN + (nn & ~15);
    float yt = 0.0f;
    #pragma unroll
    for (int s2 = 0; s2 < 16; ++s2) yt = fmaf(Ash[b][s2][t2], vp[s2], yt);

    Y[idx] = ys + yt;
}

// ---------------------------------------------------------------------------
// Kernel 4: temporal Gram partials with LDS staging. Grid (64, 2), block 256.
// Chunk = 98 n's. G[t][s] = sum_n Qt[n*16+t]*Kt[n*16+s]
// ---------------------------------------------------------------------------
__global__ __launch_bounds__(256) void temporal_g(
    const float* __restrict__ Qt, const float* __restrict__ Kt,
    float* __restrict__ Gpart)
{
    __shared__ float qs[98 * 16], ks[98 * 16];
    int b = blockIdx.y, c = blockIdx.x;
    size_t base = (size_t)b * PB + (size_t)c * 98 * 16;
    for (int i = threadIdx.x; i < 392; i += 256) {
        ((float4*)qs)[i] = ((const float4*)(Qt + base))[i];
        ((float4*)ks)[i] = ((const float4*)(Kt + base))[i];
    }
    __syncthreads();

    int t = threadIdx.x >> 4, s = threadIdx.x & 15;
    float acc = 0.0f;
    #pragma unroll 2
    for (int n = 0; n < 98; ++n)
        acc = fmaf(qs[n * 16 + t], ks[n * 16 + s], acc);
    Gpart[(size_t)(b * 64 + c) * 256 + threadIdx.x] = acc;
}

// ---------------------------------------------------------------------------
// Kernel 5: reduce Gram partials + row softmax (WITH max: logit std ~ 20)
// ---------------------------------------------------------------------------
__global__ __launch_bounds__(256) void temporal_soft(
    const float* __restrict__ Gpart, float* __restrict__ At)
{
    int b = blockIdx.x;
    __shared__ float L[256];
    float acc = 0.0f;
    for (int c = 0; c < 64; ++c)
        acc += Gpart[(size_t)(b * 64 + c) * 256 + threadIdx.x];
    L[threadIdx.x] = acc * 0.25f;
    __syncthreads();
    if (threadIdx.x < 16) {
        int t = threadIdx.x;
        float mx = -1e30f;
        #pragma unroll
        for (int s = 0; s < 16; ++s) mx = fmaxf(mx, L[t * 16 + s]);
        float e[16]; float sm = 0.0f;
        #pragma unroll
        for (int s = 0; s < 16; ++s) { e[s] = __expf(L[t * 16 + s] - mx); sm += e[s]; }
        float inv = 1.0f / sm;
        #pragma unroll
        for (int s = 0; s < 16; ++s) At[b * 256 + t * 16 + s] = e[s] * inv;
    }
}

// ---------------------------------------------------------------------------
// Kernel 6: final 1x1x1 conv + residual, 8x c-split for parallelism.
// thread per (b, c-group of 8, s): out[b,c,s] = x + bw[c] + sum_ci Ww[c,ci]*Y[b,ci,s]
// ---------------------------------------------------------------------------
__global__ __launch_bounds__(256) void final_proj(
    const float* __restrict__ x, const float* __restrict__ Ww,
    const float* __restrict__ bw, const float* __restrict__ Y,
    float* __restrict__ out)
{
    int g = blockIdx.x * 256 + threadIdx.x;       // < 50176 = 2*8*3136
    if (g >= 2 * 8 * S3) return;
    int s = g % S3;
    int r = g / S3;
    int cg = r & 7;
    int b = r >> 3;

    float y[32];
    #pragma unroll
    for (int ci = 0; ci < 32; ++ci) y[ci] = Y[(size_t)b * PB + (size_t)ci * S3 + s];

    #pragma unroll
    for (int cc = 0; cc < 8; ++cc) {
        int c = cg * 8 + cc;
        float acc = bw[c];
        #pragma unroll
        for (int ci = 0; ci < 32; ++ci) acc = fmaf(Ww[c * 32 + ci], y[ci], acc);
        out[(size_t)b * XB + (size_t)c * S3 + s] =
            x[(size_t)b * XB + (size_t)c * S3 + s] + acc;
    }
}

// ---------------------------------------------------------------------------
extern "C" void kernel_launch(void* const* d_in, const int* in_sizes, int n_in,
                              void* d_out, int out_size, void* d_ws, size_t ws_size,
                              hipStream_t stream)
{
    const float* x   = (const float*)d_in[0];
    const float* Wqs = (const float*)d_in[1];  const float* bqs = (const float*)d_in[2];
    const float* Wks = (const float*)d_in[3];  const float* bks = (const float*)d_in[4];
    const float* Wvs = (const float*)d_in[5];  const float* bvs = (const float*)d_in[6];
    const float* Wqt = (const float*)d_in[7];  const float* bqt = (const float*)d_in[8];
    const float* Wkt = (const float*)d_in[9];  const float* bkt = (const float*)d_in[10];
    const float* Wvt = (const float*)d_in[11]; const float* bvt = (const float*)d_in[12];
    const float* Ww  = (const float*)d_in[13]; const float* bw  = (const float*)d_in[14];

    // m-split factor chosen by available workspace:
    // floats needed = 1,438,208 + W*213,248
    int W = 16;
    if (ws_size < (size_t)(1438208 + 16 * 213248) * 4) W = 8;
    if (ws_size < (size_t)(1438208 +  8 * 213248) * 4) W = 4;
    int mPerWave = NN / W;

    float* ws  = (float*)d_ws;
    float* Qst = ws;              // 200704 (transposed spatial Q)
    float* Kst = ws + 200704;
    float* Vst = ws + 401408;
    float* Qt  = ws + 602112;     // natural layout
    float* Kt  = ws + 802816;
    float* Vt  = ws + 1003520;
    float* Y   = ws + 1204224;    // merged ys+yt
    float* Gp  = ws + 1404928;    // 32768 temporal Gram partials
    float* At  = ws + 1437696;    // 512 temporal attention
    float* Pacc = ws + 1438208;               // W*200704 spatial partial acc
    float* Pl   = Pacc + (size_t)W * 200704;  // W*12544 spatial partial l

    proj_kernel<<<dim3(25, 6, 2), 256, 0, stream>>>(
        x, Wqs, bqs, Wks, bks, Wvs, bvs, Wqt, bqt, Wkt, bkt, Wvt, bvt,
        Qst, Kst, Vst, Qt, Kt, Vt);

    temporal_g<<<dim3(64, 2), 256, 0, stream>>>(Qt, Kt, Gp);
    temporal_soft<<<2, 256, 0, stream>>>(Gp, At);

    spatial_attn<<<dim3(98, W / 4, 2), 256, 0, stream>>>(Qst, Kst, Vst, Pacc, Pl, W, mPerWave);

    spatial_merge<<<784, 256, 0, stream>>>(Pacc, Pl, Vt, At, Y, W);

    final_proj<<<196, 256, 0, stream>>>(x, Ww, bw, Y, (float*)d_out);
}

// Round 3
// 183.478 us; speedup vs baseline: 2.7007x; 1.3942x over previous
//
#include <hip/hip_runtime.h>
#include <math.h>

// Problem constants (B=2, C=64, CI=32, T=16, H=W=14)
#define S3   3136      // per-channel spatial size = 16*196
#define PB   100352    // per-batch proj elements = 32*3136
#define XB   200704    // per-batch x elements = 64*3136
#define NN   6272      // CI*H*W = spatial attention sequence length
#define MW   7         // spatial m-split (waves per n-tile)
#define MPW  896       // m per wave = NN/MW

typedef __attribute__((ext_vector_type(8))) short bf16x8;   // 8 bf16 = 4 VGPRs
typedef __attribute__((ext_vector_type(4))) float f32x4;    // MFMA C/D

__device__ inline ushort f2bf(float f) {     // RNE f32 -> bf16
    uint u = __float_as_uint(f);
    return (ushort)((u + 0x7FFFu + ((u >> 16) & 1u)) >> 16);
}

// ---------------------------------------------------------------------------
// Kernel 1: all 6 QKV projections, 2x o-split.
//  y=0: Qspatial -> bf16 transposed [b][n][16], pre-scaled by 0.25*log2(e)
//  y=1: Kspatial -> bf16 transposed [b][n][16]
//  y=2: Vspatial -> bf16 natural    [b][t][6272]
//  y=3..5: temporal Q/K/V -> fp32 natural flat
// ---------------------------------------------------------------------------
__global__ __launch_bounds__(256) void proj_kernel(
    const float* __restrict__ x,
    const float* __restrict__ W0, const float* __restrict__ b0,
    const float* __restrict__ W1, const float* __restrict__ b1,
    const float* __restrict__ W2, const float* __restrict__ b2,
    const float* __restrict__ W3, const float* __restrict__ b3,
    const float* __restrict__ W4, const float* __restrict__ b4,
    const float* __restrict__ W5, const float* __restrict__ b5,
    ushort* __restrict__ Qb, ushort* __restrict__ Kb, ushort* __restrict__ Vb,
    float* __restrict__ Qt, float* __restrict__ Kt, float* __restrict__ Vt)
{
    const float* Wp; const float* bp;
    switch (blockIdx.y) {
        case 0:  Wp = W0; bp = b0; break;
        case 1:  Wp = W1; bp = b1; break;
        case 2:  Wp = W2; bp = b2; break;
        case 3:  Wp = W3; bp = b3; break;
        case 4:  Wp = W4; bp = b4; break;
        default: Wp = W5; bp = b5; break;
    }
    int z = blockIdx.z;               // o in [z*16, z*16+16)

    int gid = blockIdx.x * 256 + threadIdx.x;
    if (gid >= 2 * S3) return;
    int b = (gid >= S3) ? 1 : 0;
    int s = gid - b * S3;

    float xr[64];
    #pragma unroll
    for (int c = 0; c < 64; ++c) xr[c] = x[(size_t)b * XB + (size_t)c * S3 + s];

    float a[16];
    #pragma unroll
    for (int oo = 0; oo < 16; ++oo) {
        int o = z * 16 + oo;
        float acc = bp[o];
        #pragma unroll
        for (int c = 0; c < 64; ++c) acc = fmaf(Wp[o * 64 + c], xr[c], acc);
        a[oo] = acc;
    }

    if (blockIdx.y < 2) {
        // bf16 transposed [n][16]: o = z*16 + 2k + h -> t = z*8+k, n = h*S3+s
        const float sc = (blockIdx.y == 0) ? 0.36067376022224085f : 1.0f; // 0.25*log2e
        ushort* ob = (blockIdx.y == 0) ? Qb : Kb;
        #pragma unroll
        for (int h = 0; h < 2; ++h) {
            int n = h * S3 + s;
            uint u0 = f2bf(a[0 + h] * sc)  | ((uint)f2bf(a[2 + h]  * sc) << 16);
            uint u1 = f2bf(a[4 + h] * sc)  | ((uint)f2bf(a[6 + h]  * sc) << 16);
            uint u2 = f2bf(a[8 + h] * sc)  | ((uint)f2bf(a[10 + h] * sc) << 16);
            uint u3 = f2bf(a[12 + h] * sc) | ((uint)f2bf(a[14 + h] * sc) << 16);
            *(uint4*)(ob + ((size_t)(b * NN + n) * 16 + z * 8)) = make_uint4(u0, u1, u2, u3);
        }
    } else if (blockIdx.y == 2) {
        // bf16 natural [t][n]: flat j = o*S3+s -> t = o>>1, n = (o&1)*S3+s
        #pragma unroll
        for (int oo = 0; oo < 16; ++oo) {
            int o = z * 16 + oo;
            Vb[(size_t)(b * 16 + (o >> 1)) * NN + (o & 1) * S3 + s] = f2bf(a[oo]);
        }
    } else {
        float* op = (blockIdx.y == 3) ? Qt : (blockIdx.y == 4) ? Kt : Vt;
        #pragma unroll
        for (int oo = 0; oo < 16; ++oo)
            op[(size_t)b * PB + (size_t)(z * 16 + oo) * S3 + s] = a[oo];
    }
}

// ---------------------------------------------------------------------------
// Kernel 2: spatial flash attention via bf16 MFMA.
// Wave = one 16-row n-tile x one m-chunk of 896. Per 32-m iter:
//   S^T-tile = mfma(K-frag, Q-frag)  [K=32, t padded 16->32]
//   P = exp2(S^T)  (scale folded into Q)  -> bf16 -> LDS [n][m] tile
//   Y^T += mfma(V-frag, P-frag)   ;   l += mfma(ones, P-frag)
// Partials out: Pacc[((b*16+t)*7+w)*NN+n], Pl[(b*7+w)*NN+n]
// ---------------------------------------------------------------------------
__global__ __launch_bounds__(256) void spatial_attn_mfma(
    const ushort* __restrict__ Qb, const ushort* __restrict__ Kb,
    const ushort* __restrict__ Vb,
    float* __restrict__ Pacc, float* __restrict__ Pl)
{
    __shared__ ushort ptile[4][16 * 40];   // per-wave [16 n][32 m] bf16, 80B row stride

    int wave = __builtin_amdgcn_readfirstlane((int)(threadIdx.x >> 6));
    int lane = threadIdx.x & 63;
    int col  = lane & 15;                  // n-col / m-row / t-row per operand
    int kg   = lane >> 4;                  // k-group (quad)
    int b    = blockIdx.y;
    int gw   = blockIdx.x * 4 + wave;      // 0..2743
    int ntile = gw / 7;
    int w     = gw - ntile * 7;
    int nbase = ntile * 16;
    int m0    = w * MPW;

    // Q fragment (B operand of S^T mfma): B[k=t][col=n], t = kg*8+j (kg>=2 -> pad 0)
    bf16x8 qf = {0, 0, 0, 0, 0, 0, 0, 0};
    if (kg < 2)
        qf = *(const bf16x8*)(Qb + ((size_t)(b * NN + nbase + col) * 16 + kg * 8));

    const bf16x8 ones = {16256, 16256, 16256, 16256, 16256, 16256, 16256, 16256}; // bf16 1.0
    f32x4 zero4 = {0.f, 0.f, 0.f, 0.f};
    f32x4 yacc  = zero4;
    f32x4 lacc  = zero4;

    ushort* myt = ptile[wave];

    for (int it = 0; it < MPW / 32; ++it) {
        int mb = m0 + it * 32;
        // V fragment (A operand of PV mfma): A[row=t=col][k=m=kg*8+j], all 32 k real
        bf16x8 vf = *(const bf16x8*)(Vb + ((size_t)(b * 16 + col) * NN + mb + kg * 8));

        #pragma unroll
        for (int tile = 0; tile < 2; ++tile) {
            int mt = mb + tile * 16;
            // K fragment (A operand of S^T mfma): A[row=m=col][k=t=kg*8+j]
            bf16x8 kf = {0, 0, 0, 0, 0, 0, 0, 0};
            if (kg < 2)
                kf = *(const bf16x8*)(Kb + ((size_t)(b * NN + mt + col) * 16 + kg * 8));
            f32x4 st = __builtin_amdgcn_mfma_f32_16x16x32_bf16(kf, qf, zero4, 0, 0, 0);
            // P = exp2(S^T) -- C-layout: col=n, rows m = kg*4+r (consecutive)
            float p0 = __builtin_amdgcn_exp2f(st[0]);
            float p1 = __builtin_amdgcn_exp2f(st[1]);
            float p2 = __builtin_amdgcn_exp2f(st[2]);
            float p3 = __builtin_amdgcn_exp2f(st[3]);
            uint lo = f2bf(p0) | ((uint)f2bf(p1) << 16);
            uint hi = f2bf(p2) | ((uint)f2bf(p3) << 16);
            *(uint2*)(myt + (col * 40 + tile * 16 + kg * 4)) = make_uint2(lo, hi);
        }
        // P fragment (B operand): B[k=m=kg*8+j][col=n] -- same-wave LDS RAW, no barrier
        bf16x8 pf = *(bf16x8*)(myt + (col * 40 + kg * 8));
        yacc = __builtin_amdgcn_mfma_f32_16x16x32_bf16(vf, pf, yacc, 0, 0, 0);
        lacc = __builtin_amdgcn_mfma_f32_16x16x32_bf16(ones, pf, lacc, 0, 0, 0);
    }

    // Y^T C-layout: col=n, rows t = kg*4+r
    #pragma unroll
    for (int r = 0; r < 4; ++r) {
        int t = kg * 4 + r;
        Pacc[((size_t)(b * 16 + t) * MW + w) * NN + nbase + col] = yacc[r];
    }
    if (kg == 0)
        Pl[((size_t)b * MW + w) * NN + nbase + col] = lacc[0];
}

// ---------------------------------------------------------------------------
// Kernel 3: temporal Gram partials. grid (16,2); chunk = 392 n's.
// G[t][s] = sum_n Qt[n*16+t]*Kt[n*16+s]
// ---------------------------------------------------------------------------
__global__ __launch_bounds__(256) void temporal_g(
    const float* __restrict__ Qt, const float* __restrict__ Kt,
    float* __restrict__ Gp)
{
    int b = blockIdx.y, c = blockIdx.x;
    int t = threadIdx.x >> 4, s = threadIdx.x & 15;
    const float* qb = Qt + (size_t)b * PB;
    const float* kb = Kt + (size_t)b * PB;
    float acc = 0.0f;
    int n0 = c * 392;
    #pragma unroll 4
    for (int i = 0; i < 392; ++i) {
        int n = n0 + i;
        acc = fmaf(qb[n * 16 + t], kb[n * 16 + s], acc);
    }
    Gp[(size_t)(b * 16 + c) * 256 + threadIdx.x] = acc;
}

// ---------------------------------------------------------------------------
// Kernel 4: merge spatial partials (/l), compute temporal softmax in-block
// from Gram partials, fuse yt add. Y[idx] = ys + yt.
// ---------------------------------------------------------------------------
__global__ __launch_bounds__(256) void spatial_merge(
    const float* __restrict__ Pacc, const float* __restrict__ Pl,
    const float* __restrict__ Gp, const float* __restrict__ Vt,
    float* __restrict__ Y)
{
    __shared__ float Lsh[512];
    __shared__ float Ash[2][16][16];   // [b][s][t] transposed

    for (int slot = threadIdx.x; slot < 512; slot += 256) {
        int bb = slot >> 8, ts = slot & 255;
        float a = 0.0f;
        #pragma unroll
        for (int c = 0; c < 16; ++c) a += Gp[(size_t)(bb * 16 + c) * 256 + ts];
        Lsh[slot] = a * 0.25f;
    }
    __syncthreads();
    if (threadIdx.x < 32) {
        int bb = threadIdx.x >> 4, t = threadIdx.x & 15;
        const float* Lr = &Lsh[bb * 256 + t * 16];
        float mx = -1e30f;
        #pragma unroll
        for (int s = 0; s < 16; ++s) mx = fmaxf(mx, Lr[s]);
        float e[16]; float sm = 0.0f;
        #pragma unroll
        for (int s = 0; s < 16; ++s) { e[s] = __expf(Lr[s] - mx); sm += e[s]; }
        float inv = 1.0f / sm;
        #pragma unroll
        for (int s = 0; s < 16; ++s) Ash[bb][s][t] = e[s] * inv;
    }
    __syncthreads();

    int idx = blockIdx.x * 256 + threadIdx.x;     // < 200704
    int b = (idx >= PB) ? 1 : 0;
    int j = idx - b * PB;
    int t = j / NN;
    int nn = j - t * NN;

    float a = 0.0f, l = 0.0f;
    #pragma unroll
    for (int w = 0; w < MW; ++w) {
        a += Pacc[((size_t)(b * 16 + t) * MW + w) * NN + nn];
        l += Pl[((size_t)b * MW + w) * NN + nn];
    }
    float ys = a / l;

    int t2 = nn & 15;
    const float* vp = Vt + (size_t)b * PB + (size_t)t * NN + (nn & ~15);
    float yt = 0.0f;
    #pragma unroll
    for (int s2 = 0; s2 < 16; ++s2) yt = fmaf(Ash[b][s2][t2], vp[s2], yt);

    Y[idx] = ys + yt;
}

// ---------------------------------------------------------------------------
// Kernel 5: final 1x1x1 conv + residual, 8x c-split.
// ---------------------------------------------------------------------------
__global__ __launch_bounds__(256) void final_proj(
    const float* __restrict__ x, const float* __restrict__ Ww,
    const float* __restrict__ bw, const float* __restrict__ Y,
    float* __restrict__ out)
{
    int g = blockIdx.x * 256 + threadIdx.x;       // < 50176
    if (g >= 2 * 8 * S3) return;
    int s = g % S3;
    int r = g / S3;
    int cg = r & 7;
    int b = r >> 3;

    float y[32];
    #pragma unroll
    for (int ci = 0; ci < 32; ++ci) y[ci] = Y[(size_t)b * PB + (size_t)ci * S3 + s];

    #pragma unroll
    for (int cc = 0; cc < 8; ++cc) {
        int c = cg * 8 + cc;
        float acc = bw[c];
        #pragma unroll
        for (int ci = 0; ci < 32; ++ci) acc = fmaf(Ww[c * 32 + ci], y[ci], acc);
        out[(size_t)b * XB + (size_t)c * S3 + s] =
            x[(size_t)b * XB + (size_t)c * S3 + s] + acc;
    }
}

// ---------------------------------------------------------------------------
extern "C" void kernel_launch(void* const* d_in, const int* in_sizes, int n_in,
                              void* d_out, int out_size, void* d_ws, size_t ws_size,
                              hipStream_t stream)
{
    const float* x   = (const float*)d_in[0];
    const float* Wqs = (const float*)d_in[1];  const float* bqs = (const float*)d_in[2];
    const float* Wks = (const float*)d_in[3];  const float* bks = (const float*)d_in[4];
    const float* Wvs = (const float*)d_in[5];  const float* bvs = (const float*)d_in[6];
    const float* Wqt = (const float*)d_in[7];  const float* bqt = (const float*)d_in[8];
    const float* Wkt = (const float*)d_in[9];  const float* bkt = (const float*)d_in[10];
    const float* Wvt = (const float*)d_in[11]; const float* bvt = (const float*)d_in[12];
    const float* Ww  = (const float*)d_in[13]; const float* bw  = (const float*)d_in[14];

    // workspace layout (float units); total ~2.61M floats = 10.4 MB
    float* ws = (float*)d_ws;
    ushort* Qb = (ushort*)(ws);            // 200704 bf16 = 100352 fl
    ushort* Kb = (ushort*)(ws + 100352);   // 100352 fl
    ushort* Vb = (ushort*)(ws + 200704);   // 100352 fl
    float* Qt  = ws + 301056;              // 200704
    float* Kt  = ws + 501760;              // 200704
    float* Vt  = ws + 702464;              // 200704
    float* Y   = ws + 903168;              // 200704
    float* Gp  = ws + 1103872;             // 8192
    float* Pacc = ws + 1112064;            // 2*16*7*6272 = 1404928
    float* Pl   = ws + 2516992;            // 2*7*6272   = 87808

    proj_kernel<<<dim3(25, 6, 2), 256, 0, stream>>>(
        x, Wqs, bqs, Wks, bks, Wvs, bvs, Wqt, bqt, Wkt, bkt, Wvt, bvt,
        Qb, Kb, Vb, Qt, Kt, Vt);

    temporal_g<<<dim3(16, 2), 256, 0, stream>>>(Qt, Kt, Gp);

    spatial_attn_mfma<<<dim3(686, 2), 256, 0, stream>>>(Qb, Kb, Vb, Pacc, Pl);

    spatial_merge<<<784, 256, 0, stream>>>(Pacc, Pl, Gp, Vt, Y);

    final_proj<<<196, 256, 0, stream>>>(x, Ww, bw, Y, (float*)d_out);
}

// Round 4
// 142.068 us; speedup vs baseline: 3.4879x; 1.2915x over previous
//
#include <hip/hip_runtime.h>
#include <math.h>

// Problem constants (B=2, C=64, CI=32, T=16, H=W=14)
#define S3   3136      // per-channel spatial size = 16*196
#define PB   100352    // per-batch proj elements = 32*3136
#define XB   200704    // per-batch x elements = 64*3136
#define NN   6272      // CI*H*W = spatial attention sequence length
#define MW   7         // spatial m-split (waves per n-tile)
#define MPW  896       // m per wave = NN/MW
#define TGC  49        // temporal gram chunks (128 n each)

typedef __attribute__((ext_vector_type(8))) short bf16x8;   // 8 bf16 = 4 VGPRs
typedef __attribute__((ext_vector_type(4))) float f32x4;    // MFMA C/D

__device__ inline ushort f2bf(float f) {     // RNE f32 -> bf16
    uint u = __float_as_uint(f);
    return (ushort)((u + 0x7FFFu + ((u >> 16) & 1u)) >> 16);
}

// ---------------------------------------------------------------------------
// Kernel 1: all 6 QKV projections, 2x o-split.
//  y=0: Qspatial -> bf16 transposed [b][n][16], pre-scaled by 0.25*log2(e)
//  y=1: Kspatial -> bf16 transposed [b][n][16]
//  y=2: Vspatial -> bf16 natural    [b][t][6272]
//  y=3..5: temporal Q/K/V -> fp32 natural flat
// ---------------------------------------------------------------------------
__global__ __launch_bounds__(256) void proj_kernel(
    const float* __restrict__ x,
    const float* __restrict__ W0, const float* __restrict__ b0,
    const float* __restrict__ W1, const float* __restrict__ b1,
    const float* __restrict__ W2, const float* __restrict__ b2,
    const float* __restrict__ W3, const float* __restrict__ b3,
    const float* __restrict__ W4, const float* __restrict__ b4,
    const float* __restrict__ W5, const float* __restrict__ b5,
    ushort* __restrict__ Qb, ushort* __restrict__ Kb, ushort* __restrict__ Vb,
    float* __restrict__ Qt, float* __restrict__ Kt, float* __restrict__ Vt)
{
    const float* Wp; const float* bp;
    switch (blockIdx.y) {
        case 0:  Wp = W0; bp = b0; break;
        case 1:  Wp = W1; bp = b1; break;
        case 2:  Wp = W2; bp = b2; break;
        case 3:  Wp = W3; bp = b3; break;
        case 4:  Wp = W4; bp = b4; break;
        default: Wp = W5; bp = b5; break;
    }
    int z = blockIdx.z;               // o in [z*16, z*16+16)

    int gid = blockIdx.x * 256 + threadIdx.x;
    if (gid >= 2 * S3) return;
    int b = (gid >= S3) ? 1 : 0;
    int s = gid - b * S3;

    float xr[64];
    #pragma unroll
    for (int c = 0; c < 64; ++c) xr[c] = x[(size_t)b * XB + (size_t)c * S3 + s];

    float a[16];
    #pragma unroll
    for (int oo = 0; oo < 16; ++oo) {
        int o = z * 16 + oo;
        float acc = bp[o];
        #pragma unroll
        for (int c = 0; c < 64; ++c) acc = fmaf(Wp[o * 64 + c], xr[c], acc);
        a[oo] = acc;
    }

    if (blockIdx.y < 2) {
        // bf16 transposed [n][16]: o = z*16 + 2k + h -> t = z*8+k, n = h*S3+s
        const float sc = (blockIdx.y == 0) ? 0.36067376022224085f : 1.0f; // 0.25*log2e
        ushort* ob = (blockIdx.y == 0) ? Qb : Kb;
        #pragma unroll
        for (int h = 0; h < 2; ++h) {
            int n = h * S3 + s;
            uint u0 = f2bf(a[0 + h] * sc)  | ((uint)f2bf(a[2 + h]  * sc) << 16);
            uint u1 = f2bf(a[4 + h] * sc)  | ((uint)f2bf(a[6 + h]  * sc) << 16);
            uint u2 = f2bf(a[8 + h] * sc)  | ((uint)f2bf(a[10 + h] * sc) << 16);
            uint u3 = f2bf(a[12 + h] * sc) | ((uint)f2bf(a[14 + h] * sc) << 16);
            *(uint4*)(ob + ((size_t)(b * NN + n) * 16 + z * 8)) = make_uint4(u0, u1, u2, u3);
        }
    } else if (blockIdx.y == 2) {
        // bf16 natural [t][n]: flat j = o*S3+s -> t = o>>1, n = (o&1)*S3+s
        #pragma unroll
        for (int oo = 0; oo < 16; ++oo) {
            int o = z * 16 + oo;
            Vb[(size_t)(b * 16 + (o >> 1)) * NN + (o & 1) * S3 + s] = f2bf(a[oo]);
        }
    } else {
        float* op = (blockIdx.y == 3) ? Qt : (blockIdx.y == 4) ? Kt : Vt;
        #pragma unroll
        for (int oo = 0; oo < 16; ++oo)
            op[(size_t)b * PB + (size_t)(z * 16 + oo) * S3 + s] = a[oo];
    }
}

// ---------------------------------------------------------------------------
// Kernel 2 (heterogeneous): blocks x<686: spatial flash attention via bf16
// MFMA (verified round 3); blocks x>=686: temporal Gram partials from
// LDS-staged chunks of 128 n.
// ---------------------------------------------------------------------------
__global__ __launch_bounds__(256) void attn_kernel(
    const ushort* __restrict__ Qb, const ushort* __restrict__ Kb,
    const ushort* __restrict__ Vb, const float* __restrict__ Qt,
    const float* __restrict__ Kt,
    float* __restrict__ Pacc, float* __restrict__ Pl, float* __restrict__ Gp)
{
    __shared__ ushort ptile[4][16 * 40];   // spatial: per-wave P tile
    __shared__ float qs[128 * 16], ks[128 * 16];   // temporal staging

    int b = blockIdx.y;

    if (blockIdx.x >= 686) {
        // ---- temporal Gram chunk ----
        int c = blockIdx.x - 686;            // 0..48
        size_t base = (size_t)b * PB + (size_t)c * 2048;
        for (int i = threadIdx.x; i < 512; i += 256) {
            ((float4*)qs)[i] = ((const float4*)(Qt + base))[i];
            ((float4*)ks)[i] = ((const float4*)(Kt + base))[i];
        }
        __syncthreads();
        int t = threadIdx.x >> 4, s = threadIdx.x & 15;
        float acc = 0.0f;
        #pragma unroll 8
        for (int n = 0; n < 128; ++n)
            acc = fmaf(qs[n * 16 + t], ks[n * 16 + s], acc);
        Gp[(size_t)(b * TGC + c) * 256 + threadIdx.x] = acc;
        return;
    }

    // ---- spatial flash attention (same numerics as round 3) ----
    int wave = __builtin_amdgcn_readfirstlane((int)(threadIdx.x >> 6));
    int lane = threadIdx.x & 63;
    int col  = lane & 15;
    int kg   = lane >> 4;
    int gw   = blockIdx.x * 4 + wave;      // 0..2743
    int ntile = gw / 7;
    int w     = gw - ntile * 7;
    int nbase = ntile * 16;
    int m0    = w * MPW;

    bf16x8 qf = {0, 0, 0, 0, 0, 0, 0, 0};
    if (kg < 2)
        qf = *(const bf16x8*)(Qb + ((size_t)(b * NN + nbase + col) * 16 + kg * 8));

    const bf16x8 ones = {16256, 16256, 16256, 16256, 16256, 16256, 16256, 16256};
    f32x4 zero4 = {0.f, 0.f, 0.f, 0.f};
    f32x4 yacc  = zero4;
    f32x4 lacc  = zero4;

    ushort* myt = ptile[wave];

    for (int it = 0; it < MPW / 32; ++it) {
        int mb = m0 + it * 32;
        bf16x8 vf = *(const bf16x8*)(Vb + ((size_t)(b * 16 + col) * NN + mb + kg * 8));

        #pragma unroll
        for (int tile = 0; tile < 2; ++tile) {
            int mt = mb + tile * 16;
            bf16x8 kf = {0, 0, 0, 0, 0, 0, 0, 0};
            if (kg < 2)
                kf = *(const bf16x8*)(Kb + ((size_t)(b * NN + mt + col) * 16 + kg * 8));
            f32x4 st = __builtin_amdgcn_mfma_f32_16x16x32_bf16(kf, qf, zero4, 0, 0, 0);
            float p0 = __builtin_amdgcn_exp2f(st[0]);
            float p1 = __builtin_amdgcn_exp2f(st[1]);
            float p2 = __builtin_amdgcn_exp2f(st[2]);
            float p3 = __builtin_amdgcn_exp2f(st[3]);
            uint lo = f2bf(p0) | ((uint)f2bf(p1) << 16);
            uint hi = f2bf(p2) | ((uint)f2bf(p3) << 16);
            *(uint2*)(myt + (col * 40 + tile * 16 + kg * 4)) = make_uint2(lo, hi);
        }
        bf16x8 pf = *(bf16x8*)(myt + (col * 40 + kg * 8));
        yacc = __builtin_amdgcn_mfma_f32_16x16x32_bf16(vf, pf, yacc, 0, 0, 0);
        lacc = __builtin_amdgcn_mfma_f32_16x16x32_bf16(ones, pf, lacc, 0, 0, 0);
    }

    #pragma unroll
    for (int r = 0; r < 4; ++r) {
        int t = kg * 4 + r;
        Pacc[((size_t)(b * 16 + t) * MW + w) * NN + nbase + col] = yacc[r];
    }
    if (kg == 0)
        Pl[((size_t)b * MW + w) * NN + nbase + col] = lacc[0];
}

// ---------------------------------------------------------------------------
// Kernel 3: fused merge + temporal softmax + yt + output projection + residual.
// Block = (b, 16-s chunk). Grid (196, 2).
//  A: reduce Gp -> logits -> softmax -> Ash[s2][t2]; stage Ww -> Wsh[c][ci].
//  B: Ysh[ss][ci] = ys(merge of 7 partials / l) + yt.
//  C: out[b,c,s] = x + bw[c] + sum_ci Wsh[c][ci]*Ysh[ss][ci]
// ---------------------------------------------------------------------------
__global__ __launch_bounds__(256) void merge_final(
    const float* __restrict__ Pacc, const float* __restrict__ Pl,
    const float* __restrict__ Gp, const float* __restrict__ Vt,
    const float* __restrict__ x, const float* __restrict__ Ww,
    const float* __restrict__ bw, float* __restrict__ out)
{
    __shared__ float Lsh[256];
    __shared__ float Ash[16][17];    // [s2][t2]
    __shared__ float Wsh[64 * 36];   // [c][ci], stride 36 (16B-aligned, 2-way banks)
    __shared__ float Ysh[16 * 36];   // [ss][ci], stride 36

    int b  = blockIdx.y;
    int sc = blockIdx.x;             // s chunk: [sc*16, sc*16+16)

    // --- phase A ---
    {
        float a = 0.0f;
        for (int c = 0; c < TGC; ++c)
            a += Gp[(size_t)(b * TGC + c) * 256 + threadIdx.x];
        Lsh[threadIdx.x] = a * 0.25f;
        for (int i = threadIdx.x; i < 2048; i += 256)
            Wsh[(i >> 5) * 36 + (i & 31)] = Ww[i];
    }
    __syncthreads();
    if (threadIdx.x < 16) {
        int t = threadIdx.x;
        const float* Lr = &Lsh[t * 16];
        float mx = -1e30f;
        #pragma unroll
        for (int s = 0; s < 16; ++s) mx = fmaxf(mx, Lr[s]);
        float e[16]; float sm = 0.0f;
        #pragma unroll
        for (int s = 0; s < 16; ++s) { e[s] = __expf(Lr[s] - mx); sm += e[s]; }
        float inv = 1.0f / sm;
        #pragma unroll
        for (int s = 0; s < 16; ++s) Ash[s][t] = e[s] * inv;
    }
    __syncthreads();

    // --- phase B: 512 Y values, 2 per thread ---
    #pragma unroll
    for (int k = 0; k < 2; ++k) {
        int idx = threadIdx.x + k * 256;      // 0..511
        int ss = idx & 15;
        int ci = idx >> 4;                    // 0..31
        int s  = sc * 16 + ss;
        int t  = ci >> 1;
        int nn = (ci & 1) * S3 + s;

        float a = 0.0f, l = 0.0f;
        #pragma unroll
        for (int w = 0; w < MW; ++w) {
            a += Pacc[((size_t)(b * 16 + t) * MW + w) * NN + nn];
            l += Pl[((size_t)b * MW + w) * NN + nn];
        }
        float ys = a / l;

        int t2 = nn & 15;
        const float4* vp = (const float4*)(Vt + (size_t)b * PB + (size_t)t * NN + (nn & ~15));
        float4 v0 = vp[0], v1 = vp[1], v2 = vp[2], v3 = vp[3];
        float yt = Ash[0][t2] * v0.x;
        yt = fmaf(Ash[1][t2],  v0.y, yt); yt = fmaf(Ash[2][t2],  v0.z, yt);
        yt = fmaf(Ash[3][t2],  v0.w, yt); yt = fmaf(Ash[4][t2],  v1.x, yt);
        yt = fmaf(Ash[5][t2],  v1.y, yt); yt = fmaf(Ash[6][t2],  v1.z, yt);
        yt = fmaf(Ash[7][t2],  v1.w, yt); yt = fmaf(Ash[8][t2],  v2.x, yt);
        yt = fmaf(Ash[9][t2],  v2.y, yt); yt = fmaf(Ash[10][t2], v2.z, yt);
        yt = fmaf(Ash[11][t2], v2.w, yt); yt = fmaf(Ash[12][t2], v3.x, yt);
        yt = fmaf(Ash[13][t2], v3.y, yt); yt = fmaf(Ash[14][t2], v3.z, yt);
        yt = fmaf(Ash[15][t2], v3.w, yt);

        Ysh[ss * 36 + ci] = ys + yt;
    }
    __syncthreads();

    // --- phase C: 64c x 16ss outputs, 4 per thread ---
    int ss = threadIdx.x & 15;
    int cg = threadIdx.x >> 4;               // 0..15, c = cg*4 + k
    int s  = sc * 16 + ss;

    float acc[4];
    #pragma unroll
    for (int k = 0; k < 4; ++k) acc[k] = bw[cg * 4 + k];

    #pragma unroll
    for (int cb = 0; cb < 32; cb += 4) {
        float4 y4 = *(const float4*)&Ysh[ss * 36 + cb];
        #pragma unroll
        for (int k = 0; k < 4; ++k) {
            float4 w4 = *(const float4*)&Wsh[(cg * 4 + k) * 36 + cb];
            acc[k] = fmaf(w4.x, y4.x, acc[k]);
            acc[k] = fmaf(w4.y, y4.y, acc[k]);
            acc[k] = fmaf(w4.z, y4.z, acc[k]);
            acc[k] = fmaf(w4.w, y4.w, acc[k]);
        }
    }

    #pragma unroll
    for (int k = 0; k < 4; ++k) {
        int c = cg * 4 + k;
        size_t o = (size_t)b * XB + (size_t)c * S3 + s;
        out[o] = x[o] + acc[k];
    }
}

// ---------------------------------------------------------------------------
extern "C" void kernel_launch(void* const* d_in, const int* in_sizes, int n_in,
                              void* d_out, int out_size, void* d_ws, size_t ws_size,
                              hipStream_t stream)
{
    const float* x   = (const float*)d_in[0];
    const float* Wqs = (const float*)d_in[1];  const float* bqs = (const float*)d_in[2];
    const float* Wks = (const float*)d_in[3];  const float* bks = (const float*)d_in[4];
    const float* Wvs = (const float*)d_in[5];  const float* bvs = (const float*)d_in[6];
    const float* Wqt = (const float*)d_in[7];  const float* bqt = (const float*)d_in[8];
    const float* Wkt = (const float*)d_in[9];  const float* bkt = (const float*)d_in[10];
    const float* Wvt = (const float*)d_in[11]; const float* bvt = (const float*)d_in[12];
    const float* Ww  = (const float*)d_in[13]; const float* bw  = (const float*)d_in[14];

    // workspace layout (float units); total ~2.42M floats = 9.7 MB
    float* ws = (float*)d_ws;
    ushort* Qb = (ushort*)(ws);            // 200704 bf16
    ushort* Kb = (ushort*)(ws + 100352);
    ushort* Vb = (ushort*)(ws + 200704);
    float* Qt  = ws + 301056;              // 200704
    float* Kt  = ws + 501760;
    float* Vt  = ws + 702464;
    float* Gp  = ws + 903168;              // 2*49*256 = 25088
    float* Pacc = ws + 928256;             // 2*16*7*6272 = 1404928
    float* Pl   = ws + 2333184;            // 2*7*6272 = 87808

    proj_kernel<<<dim3(25, 6, 2), 256, 0, stream>>>(
        x, Wqs, bqs, Wks, bks, Wvs, bvs, Wqt, bqt, Wkt, bkt, Wvt, bvt,
        Qb, Kb, Vb, Qt, Kt, Vt);

    attn_kernel<<<dim3(686 + TGC, 2), 256, 0, stream>>>(
        Qb, Kb, Vb, Qt, Kt, Pacc, Pl, Gp);

    merge_final<<<dim3(196, 2), 256, 0, stream>>>(
        Pacc, Pl, Gp, Vt, x, Ww, bw, (float*)d_out);
}